// Round 4
// baseline (854.029 us; speedup 1.0000x reference)
//
#include <hip/hip_runtime.h>
#include <hip/hip_bf16.h>

#define B_ 128
#define L_ 4096
#define D_ 128
#define E_ 64

typedef __attribute__((ext_vector_type(8))) short short8;
typedef __attribute__((ext_vector_type(4))) float floatx4;

static __device__ __forceinline__ unsigned short f2bf(float x) {
  __hip_bfloat16 h = __float2bfloat16(x);
  union { __hip_bfloat16 h; unsigned short u; } c; c.h = h; return c.u;
}
static __device__ __forceinline__ float bf2f(unsigned short u) {
  union { unsigned short u; __hip_bfloat16 h; } c; c.u = u; return __bfloat162float(c.h);
}

// One kernel does everything. Grid = B_*32 blocks of 256.
// Block (b, lt): computes scores[b][lt*128 .. lt*128+127] via split-bf16 MFMA
// (Wr1 fragments converted from fp32 in registers; cvec recomputed per block).
// The last block of each batch (atomic counter) becomes the finalizer:
// entmax bisection + support gather + selu + L2-norm, reusing the staging LDS.
__global__ __launch_bounds__(256, 2) void fused(
    const float* __restrict__ R, const float* __restrict__ alpha,
    const float* __restrict__ target, const float* __restrict__ Wr1,
    const float* __restrict__ Wr2, const float* __restrict__ Wr3,
    const float* __restrict__ bias_r, const float* __restrict__ Wf_w,
    const float* __restrict__ Wf_b, float* __restrict__ scores,
    int* __restrict__ cnt, float* __restrict__ out) {
  __shared__ __align__(16) unsigned short sAhi[16384];  // 32 KB
  __shared__ __align__(16) unsigned short sAlo[16384];  // 32 KB
  __shared__ float tg[D_];
  __shared__ float qv[E_];
  __shared__ float scvec[D_];
  __shared__ float sred[2][4];
  __shared__ int sflag, scnt, smcnt;

  const int b = blockIdx.x >> 5;
  const int lt = blockIdx.x & 31;
  const int t = threadIdx.x;
  const int wave = t >> 6, lane = t & 63;
  const int col = lane & 15, quad = lane >> 4;

  if (t < D_) tg[t] = target[b * D_ + t];

  // ---- stage A-tile fragments (R tile) hi/lo, lane-owned 16B slots: conflict-free
  const float* Rbase = R + ((size_t)b * L_ + (size_t)lt * 128) * D_;
  #pragma unroll
  for (int i = 0; i < 8; ++i) {
    const int mt = wave * 2 + (i >> 2);
    const int ks = i & 3;
    const int row = mt * 16 + col;
    const int c0 = ks * 32 + quad * 8;
    const float4* p = (const float4*)(Rbase + (size_t)row * D_ + c0);
    float4 v0 = p[0], v1 = p[1];
    float vv[8] = {v0.x, v0.y, v0.z, v0.w, v1.x, v1.y, v1.z, v1.w};
    union { unsigned short u[8]; short8 v; } H, Lo;
    #pragma unroll
    for (int j = 0; j < 8; ++j) {
      unsigned short h = f2bf(vv[j]);
      H.u[j] = h;
      Lo.u[j] = f2bf(vv[j] - bf2f(h));
    }
    const int base = ((mt * 4 + ks) * 64 + lane) * 8;
    *(short8*)(sAhi + base) = H.v;
    *(short8*)(sAlo + base) = Lo.v;
  }

  // ---- B fragments straight from fp32 Wr1 (L2-hot), split hi/lo in registers
  short8 bh[2][4], bl[2][4];
  #pragma unroll
  for (int n = 0; n < 2; ++n)
    #pragma unroll
    for (int ks = 0; ks < 4; ++ks) {
      const int e = (wave * 2 + n) * 16 + col;
      const int c0 = ks * 32 + quad * 8;
      const float4* p = (const float4*)(Wr1 + e * D_ + c0);
      float4 v0 = p[0], v1 = p[1];
      float vv[8] = {v0.x, v0.y, v0.z, v0.w, v1.x, v1.y, v1.z, v1.w};
      union { unsigned short u[8]; short8 v; } H, Lo;
      #pragma unroll
      for (int j = 0; j < 8; ++j) {
        unsigned short h = f2bf(vv[j]);
        H.u[j] = h;
        Lo.u[j] = f2bf(vv[j] - bf2f(h));
      }
      bh[n][ks] = H.v;
      bl[n][ks] = Lo.v;
    }

  floatx4 acc[8][2];
  #pragma unroll
  for (int mt = 0; mt < 8; ++mt)
    #pragma unroll
    for (int n = 0; n < 2; ++n) acc[mt][n] = (floatx4){0.f, 0.f, 0.f, 0.f};

  __syncthreads();  // tg + A-tile published

  // ---- cvec for this batch (redundant per block; ~16k MAC total, L2-hot weights)
  if (t < E_) {
    float s = Wf_b[t];
    #pragma unroll 8
    for (int d = 0; d < D_; ++d) s += tg[d] * Wf_w[t * D_ + d];
    qv[t] = s;
  }
  __syncthreads();
  if (t < D_) {
    float s = bias_r[t];
    #pragma unroll 8
    for (int e = 0; e < E_; ++e) s += qv[e] * Wr2[t * E_ + e];
    scvec[t] = s;
  }

  // ---- MFMA main loop (split-bf16: hi*hi + lo*hi + hi*lo)
  #pragma unroll
  for (int mt = 0; mt < 8; ++mt) {
    #pragma unroll
    for (int ks = 0; ks < 4; ++ks) {
      const int ai = ((mt * 4 + ks) * 64 + lane) * 8;
      short8 ah = *(const short8*)(sAhi + ai);
      short8 al = *(const short8*)(sAlo + ai);
      #pragma unroll
      for (int n = 0; n < 2; ++n) {
        acc[mt][n] = __builtin_amdgcn_mfma_f32_16x16x32_bf16(ah, bh[n][ks], acc[mt][n], 0, 0, 0);
        acc[mt][n] = __builtin_amdgcn_mfma_f32_16x16x32_bf16(al, bh[n][ks], acc[mt][n], 0, 0, 0);
        acc[mt][n] = __builtin_amdgcn_mfma_f32_16x16x32_bf16(ah, bl[n][ks], acc[mt][n], 0, 0, 0);
      }
    }
  }

  __syncthreads();  // A-tile dead (LDS reusable), scvec published

  // ---- epilogue: score[m] = sum_e Wr3[e]*relu(C[m][e] + cvec[e])
  float w3[2], cb[2];
  #pragma unroll
  for (int n = 0; n < 2; ++n) {
    const int e = (wave * 2 + n) * 16 + col;
    w3[n] = Wr3[e];
    cb[n] = scvec[e];
  }
  float part[8][4];
  #pragma unroll
  for (int mt = 0; mt < 8; ++mt)
    #pragma unroll
    for (int r = 0; r < 4; ++r) {
      float s = 0.f;
      #pragma unroll
      for (int n = 0; n < 2; ++n)
        s += w3[n] * fmaxf(acc[mt][n][r] + cb[n], 0.f);
      s += __shfl_xor(s, 1, 64);
      s += __shfl_xor(s, 2, 64);
      s += __shfl_xor(s, 4, 64);
      s += __shfl_xor(s, 8, 64);
      part[mt][r] = s;
    }
  float* red = (float*)sAhi;  // [4 waves][128 rows]
  if (col == 0) {
    #pragma unroll
    for (int mt = 0; mt < 8; ++mt)
      #pragma unroll
      for (int r = 0; r < 4; ++r)
        red[wave * 128 + mt * 16 + quad * 4 + r] = part[mt][r];
  }
  __syncthreads();
  if (t < 128) {
    float s = (red[t] + red[128 + t]) + (red[256 + t] + red[384 + t]);
    scores[(size_t)b * L_ + lt * 128 + t] = s;
  }

  // ---- elect finalizer (last completed block of this batch)
  __syncthreads();               // drains the score stores (vmcnt 0 before barrier)
  if (t == 0) {
    __threadfence();             // release: tile visible device-wide
    sflag = atomicAdd(&cnt[b], 1);
  }
  __syncthreads();
  if (sflag != 31) return;
  __threadfence();               // acquire: no stale score lines

  // ================= finalizer: entmax bisection + gather =================
  float* sX = (float*)sAhi;                    // 4096 floats
  float* sW = (float*)sAhi + 4096;             // 4096 floats
  unsigned short* sI = sAlo;                   // 4096 u16
  unsigned short* sJ = sAlo + 4096;            // 4096 u16
  float* ppart = (float*)(sAlo + 8192);        // 256 floats

  const float am1 = alpha[b] - 1.0f;
  const float inv = 1.0f / am1;
  const float* S = scores + (size_t)b * L_;
  float Xs[16];
  #pragma unroll
  for (int i = 0; i < 16; ++i) Xs[i] = S[i * 256 + t] * am1;
  if (t == 0) { scnt = 0; smcnt = 0; }

  // block max
  float mx = Xs[0];
  #pragma unroll
  for (int i = 1; i < 16; ++i) mx = fmaxf(mx, Xs[i]);
  #pragma unroll
  for (int m = 32; m >= 1; m >>= 1) mx = fmaxf(mx, __shfl_xor(mx, m, 64));
  if (lane == 0) sred[0][wave] = mx;
  __syncthreads();
  mx = fmaxf(fmaxf(sred[0][0], sred[0][1]), fmaxf(sred[0][2], sred[0][3]));

  const float tau_lo0 = mx - 1.0f;
  // exact pruning: Xs <= mx-1 clip to 0 for every evaluated tau
  #pragma unroll
  for (int i = 0; i < 16; ++i) {
    if (Xs[i] > tau_lo0) {
      int pos = atomicAdd(&scnt, 1);
      sX[pos] = Xs[i];
      sI[pos] = (unsigned short)(i * 256 + t);
    }
  }
  __syncthreads();
  const int n = scnt;

  float tau_lo = tau_lo0;
  float dm = (mx - exp2f(-12.0f * am1)) - tau_lo;  // tau_hi - tau_lo

  int pc = 1;
  auto sumP = [&](float tau) -> float {
    const int par = pc & 1;
    ++pc;
    float s = 0.f;
    for (int k = t; k < n; k += 256) {
      float u = sX[k] - tau;
      if (u > 0.f) s += exp2f(inv * __log2f(u));
    }
    #pragma unroll
    for (int m = 32; m >= 1; m >>= 1) s += __shfl_xor(s, m, 64);
    if (lane == 0) sred[par][wave] = s;
    __syncthreads();
    return (sred[par][0] + sred[par][1]) + (sred[par][2] + sred[par][3]);
  };

  const float f_lo = sumP(tau_lo) - 1.0f;
  float tau_m = tau_lo;
  for (int it = 0; it < 40; ++it) {  // iters 41..50 are below fp32 resolution
    dm *= 0.5f;
    tau_m = tau_lo + dm;
    float f_m = sumP(tau_m) - 1.0f;
    if (f_m * f_lo >= 0.f) tau_lo = tau_m;  // uniform branch
  }

  // final p, compact support, normalization sum
  float s = 0.f;
  for (int k = t; k < n; k += 256) {
    float u = sX[k] - tau_m;
    if (u > 0.f) {
      float p = exp2f(inv * __log2f(u));
      s += p;
      int pos = atomicAdd(&smcnt, 1);
      sJ[pos] = sI[k];
      sW[pos] = p;
    }
  }
  {
    const int par = pc & 1;
    ++pc;
    #pragma unroll
    for (int m = 32; m >= 1; m >>= 1) s += __shfl_xor(s, m, 64);
    if (lane == 0) sred[par][wave] = s;
    __syncthreads();  // publishes sJ/sW/smcnt too
    s = (sred[par][0] + sred[par][1]) + (sred[par][2] + sred[par][3]);
  }
  const int ns = smcnt;
  const float rs = 1.0f / s;

  // gather: 2 groups of 128 threads split the support list
  const float* Rb = R + (size_t)b * L_ * D_;
  const int g = t >> 7, c = t & 127;
  float a0 = 0.f;
  int k = g;
  for (; k + 6 < ns; k += 8) {
    int i0 = sJ[k], i1 = sJ[k + 2], i2 = sJ[k + 4], i3 = sJ[k + 6];
    float w0 = sW[k], w1 = sW[k + 2], w2 = sW[k + 4], w3v = sW[k + 6];
    a0 += w0 * Rb[(size_t)i0 * D_ + c] + w1 * Rb[(size_t)i1 * D_ + c]
        + w2 * Rb[(size_t)i2 * D_ + c] + w3v * Rb[(size_t)i3 * D_ + c];
  }
  for (; k < ns; k += 2) a0 += sW[k] * Rb[(size_t)sJ[k] * D_ + c];
  __syncthreads();
  ppart[t] = a0;
  __syncthreads();
  float r = 0.f;
  if (t < 128) {
    float a2 = (ppart[t] + ppart[t + 128]) * rs;
    const float sc = 1.0507009873554805f, al = 1.6732632423543772f;
    r = a2 > 0.f ? sc * a2 : sc * al * (expf(a2) - 1.0f);
  }
  float qq = r * r;
  #pragma unroll
  for (int m = 32; m >= 1; m >>= 1) qq += __shfl_xor(qq, m, 64);
  if (lane == 0) sred[0][wave] = qq;
  __syncthreads();
  if (t < 128) {
    float nrm = sqrtf((sred[0][0] + sred[0][1]) + (sred[0][2] + sred[0][3]));
    out[b * D_ + t] = r / nrm;
  }
}

extern "C" void kernel_launch(void* const* d_in, const int* in_sizes, int n_in,
                              void* d_out, int out_size, void* d_ws, size_t ws_size,
                              hipStream_t stream) {
  const float* R      = (const float*)d_in[0];
  const float* alpha  = (const float*)d_in[1];
  const float* target = (const float*)d_in[2];
  const float* Wr1    = (const float*)d_in[3];
  const float* Wr2    = (const float*)d_in[4];
  const float* Wr3    = (const float*)d_in[5];
  const float* bias_r = (const float*)d_in[6];
  const float* Wf_w   = (const float*)d_in[7];
  const float* Wf_b   = (const float*)d_in[8];
  float* out = (float*)d_out;

  char* ws = (char*)d_ws;
  float* scores = (float*)ws;                 // 2 MB
  int*   cnt    = (int*)(ws + 2097152);       // 512 B

  hipMemsetAsync(cnt, 0, B_ * sizeof(int), stream);
  hipLaunchKernelGGL(fused, dim3(B_ * 32), dim3(256), 0, stream,
                     R, alpha, target, Wr1, Wr2, Wr3, bias_r, Wf_w, Wf_b,
                     scores, cnt, out);
}

// Round 5
// 510.548 us; speedup vs baseline: 1.6728x; 1.6728x over previous
//
#include <hip/hip_runtime.h>
#include <hip/hip_bf16.h>

#define B_ 128
#define L_ 4096
#define D_ 128
#define E_ 64

typedef __attribute__((ext_vector_type(8))) short short8;
typedef __attribute__((ext_vector_type(4))) float floatx4;

static __device__ __forceinline__ unsigned short f2bf(float x) {
  __hip_bfloat16 h = __float2bfloat16(x);
  union { __hip_bfloat16 h; unsigned short u; } c; c.h = h; return c.u;
}
static __device__ __forceinline__ float bf2f(unsigned short u) {
  union { unsigned short u; __hip_bfloat16 h; } c; c.u = u; return __bfloat162float(c.h);
}

// ---------------- prep: blocks 0..63 split+swizzle Wr1; blocks 64..127 compute
// cvec[b][d] = bias_r[d] + sum_e (target[b]·Wf_w[e] + Wf_b[e]) * Wr2[d][e]
__global__ __launch_bounds__(256) void prep(
    const float* __restrict__ Wr1, unsigned short* __restrict__ hi,
    unsigned short* __restrict__ lo, const float* __restrict__ target,
    const float* __restrict__ Wr2, const float* __restrict__ bias_r,
    const float* __restrict__ Wf_w, const float* __restrict__ Wf_b,
    float* __restrict__ cvec) {
  if (blockIdx.x < 64) {
    // B operand fragments: B[k=d][n=e] = Wr1[e][d]; dst [nt(8)][ks(4)][lane(64)][j(8)]
    int t = blockIdx.x * 256 + threadIdx.x;  // 0..16383
    int j = t & 7, lane = (t >> 3) & 63, ks = (t >> 9) & 3, nt = t >> 11;
    int e = nt * 16 + (lane & 15);
    int d = ks * 32 + (lane >> 4) * 8 + j;
    float x = Wr1[e * D_ + d];
    unsigned short h = f2bf(x);
    hi[t] = h;
    lo[t] = f2bf(x - bf2f(h));
  } else {
    const int sub = threadIdx.x >> 7;           // 2 batches per block
    const int t = threadIdx.x & 127;
    const int b = (blockIdx.x - 64) * 2 + sub;
    __shared__ float tg[2][D_];
    __shared__ float q[2][E_];
    tg[sub][t] = target[b * D_ + t];
    __syncthreads();
    if (t < E_) {
      float s = Wf_b[t];
      #pragma unroll 8
      for (int d = 0; d < D_; ++d) s += tg[sub][d] * Wf_w[t * D_ + d];
      q[sub][t] = s;
    }
    __syncthreads();
    float s = bias_r[t];
    #pragma unroll 8
    for (int e = 0; e < E_; ++e) s += q[sub][e] * Wr2[t * E_ + e];
    cvec[b * D_ + t] = s;
  }
}

// ---------------- pass B: scores[b][l] = sum_e Wr3[e]*relu( R[b][l]·Wr1[e] + c[b][e] )
// Barrier-free, LDS-free split-bf16 MFMA GEMM.
// Waves split M: wave w owns rows [lt*128 + w*32, +32) and the FULL e=128 (N).
// A fragments load DIRECTLY from global R (lane's fragment = 32 contiguous
// bytes of one R row); B fragments from pre-split whi/wlo (L2-hot);
// epilogue reduces over e with 4 intra-quad shuffles -> direct scatter store.
__global__ __launch_bounds__(256) void pass_b(
    const float* __restrict__ R, const unsigned short* __restrict__ Whi,
    const unsigned short* __restrict__ Wlo, const float* __restrict__ cvec,
    const float* __restrict__ Wr3, float* __restrict__ scores) {
  const int b = blockIdx.x >> 5;
  const int lt = blockIdx.x & 31;
  const int t = threadIdx.x;
  const int wave = t >> 6, lane = t & 63;
  const int col = lane & 15, quad = lane >> 4;

  const float* Rw = R + ((size_t)b * L_ + (size_t)lt * 128 + wave * 32) * D_;

  floatx4 acc[2][8];
  #pragma unroll
  for (int mt = 0; mt < 2; ++mt)
    #pragma unroll
    for (int nt = 0; nt < 8; ++nt) acc[mt][nt] = (floatx4){0.f, 0.f, 0.f, 0.f};

  #pragma unroll
  for (int ks = 0; ks < 4; ++ks) {
    // A fragments for this k-step: mt in {0,1}, element A[m=col][k=quad*8+j]
    short8 ah[2], al[2];
    #pragma unroll
    for (int mt = 0; mt < 2; ++mt) {
      const float4* p = (const float4*)(Rw + (size_t)(mt * 16 + col) * D_ + ks * 32 + quad * 8);
      float4 v0 = p[0], v1 = p[1];
      float vv[8] = {v0.x, v0.y, v0.z, v0.w, v1.x, v1.y, v1.z, v1.w};
      union { unsigned short u[8]; short8 v; } H, Lo;
      #pragma unroll
      for (int j = 0; j < 8; ++j) {
        unsigned short h = f2bf(vv[j]);
        H.u[j] = h;
        Lo.u[j] = f2bf(vv[j] - bf2f(h));
      }
      ah[mt] = H.v;
      al[mt] = Lo.v;
    }
    #pragma unroll
    for (int nt = 0; nt < 8; ++nt) {
      const int off = ((nt * 4 + ks) * 64 + lane) * 8;
      short8 bhv = *(const short8*)(Whi + off);
      short8 blv = *(const short8*)(Wlo + off);
      #pragma unroll
      for (int mt = 0; mt < 2; ++mt) {
        acc[mt][nt] = __builtin_amdgcn_mfma_f32_16x16x32_bf16(ah[mt], bhv, acc[mt][nt], 0, 0, 0);
        acc[mt][nt] = __builtin_amdgcn_mfma_f32_16x16x32_bf16(al[mt], bhv, acc[mt][nt], 0, 0, 0);
        acc[mt][nt] = __builtin_amdgcn_mfma_f32_16x16x32_bf16(ah[mt], blv, acc[mt][nt], 0, 0, 0);
      }
    }
  }

  // epilogue: score[m] = sum_e Wr3[e]*relu(C[m][e] + cvec[e])
  // C/D layout: col = lane&15 (e within nt), row = quad*4 + r.
  float w3v[8], cbv[8];
  #pragma unroll
  for (int nt = 0; nt < 8; ++nt) {
    const int e = nt * 16 + col;
    w3v[nt] = Wr3[e];
    cbv[nt] = cvec[b * D_ + e];
  }
  float* Sout = scores + (size_t)b * L_ + lt * 128 + wave * 32;
  #pragma unroll
  for (int mt = 0; mt < 2; ++mt)
    #pragma unroll
    for (int r = 0; r < 4; ++r) {
      float s = 0.f;
      #pragma unroll
      for (int nt = 0; nt < 8; ++nt)
        s += w3v[nt] * fmaxf(acc[mt][nt][r] + cbv[nt], 0.f);
      s += __shfl_xor(s, 1, 64);
      s += __shfl_xor(s, 2, 64);
      s += __shfl_xor(s, 4, 64);
      s += __shfl_xor(s, 8, 64);
      if (col == 0) Sout[mt * 16 + quad * 4 + r] = s;
    }
}

// ---------------- fused pass C+D: exact candidate pruning + 32-iter bisection
// (dm < 2^-32 of bracket: p bit-negligible vs 50-iter ref), support gather,
// selu, L2-normalize. 256 threads.
__global__ __launch_bounds__(256) void pass_cd(
    const float* __restrict__ scores, const float* __restrict__ alpha,
    const float* __restrict__ R, float* __restrict__ out) {
  const int b = blockIdx.x, t = threadIdx.x;
  const int wave = t >> 6, lane = t & 63;
  __shared__ float sX[L_];            // candidate Xs (16 KB)
  __shared__ unsigned short sI[L_];   // candidate indices (8 KB)
  __shared__ float sW[L_];            // support weights (16 KB)
  __shared__ unsigned short sJ[L_];   // support indices (8 KB)
  __shared__ float ppart[256];
  __shared__ float sred[2][4];
  __shared__ int scnt, smcnt;
  const float am1 = alpha[b] - 1.0f;
  const float inv = 1.0f / am1;
  const float* S = scores + (size_t)b * L_;
  float Xs[16];
  #pragma unroll
  for (int i = 0; i < 16; ++i) Xs[i] = S[i * 256 + t] * am1;
  if (t == 0) { scnt = 0; smcnt = 0; }

  // block max
  float mx = Xs[0];
  #pragma unroll
  for (int i = 1; i < 16; ++i) mx = fmaxf(mx, Xs[i]);
  #pragma unroll
  for (int m = 32; m >= 1; m >>= 1) mx = fmaxf(mx, __shfl_xor(mx, m, 64));
  if (lane == 0) sred[0][wave] = mx;
  __syncthreads();
  mx = fmaxf(fmaxf(sred[0][0], sred[0][1]), fmaxf(sred[0][2], sred[0][3]));

  const float tau_lo0 = mx - 1.0f;
  // exact pruning: Xs <= mx-1 clips to 0 for every evaluated tau
  #pragma unroll
  for (int i = 0; i < 16; ++i) {
    if (Xs[i] > tau_lo0) {
      int pos = atomicAdd(&scnt, 1);
      sX[pos] = Xs[i];
      sI[pos] = (unsigned short)(i * 256 + t);
    }
  }
  __syncthreads();
  const int n = scnt;

  float tau_lo = tau_lo0;
  float dm = (mx - exp2f(-12.0f * am1)) - tau_lo;  // tau_hi - tau_lo

  int pc = 1;
  auto sumP = [&](float tau) -> float {
    const int par = pc & 1;
    ++pc;
    float s = 0.f;
    for (int k = t; k < n; k += 256) {
      float u = sX[k] - tau;
      if (u > 0.f) s += exp2f(inv * __log2f(u));
    }
    #pragma unroll
    for (int m = 32; m >= 1; m >>= 1) s += __shfl_xor(s, m, 64);
    if (lane == 0) sred[par][wave] = s;
    __syncthreads();
    return (sred[par][0] + sred[par][1]) + (sred[par][2] + sred[par][3]);
  };

  const float f_lo = sumP(tau_lo) - 1.0f;
  float tau_m = tau_lo;
  for (int it = 0; it < 32; ++it) {
    dm *= 0.5f;
    tau_m = tau_lo + dm;
    float f_m = sumP(tau_m) - 1.0f;
    if (f_m * f_lo >= 0.f) tau_lo = tau_m;  // uniform branch
  }

  // final p, compact support, normalization sum
  float s = 0.f;
  for (int k = t; k < n; k += 256) {
    float u = sX[k] - tau_m;
    if (u > 0.f) {
      float p = exp2f(inv * __log2f(u));
      s += p;
      int pos = atomicAdd(&smcnt, 1);
      sJ[pos] = sI[k];
      sW[pos] = p;
    }
  }
  {
    const int par = pc & 1;
    ++pc;
    #pragma unroll
    for (int m = 32; m >= 1; m >>= 1) s += __shfl_xor(s, m, 64);
    if (lane == 0) sred[par][wave] = s;
    __syncthreads();  // publishes sJ/sW/smcnt too
    s = (sred[par][0] + sred[par][1]) + (sred[par][2] + sred[par][3]);
  }
  const int ns = smcnt;
  const float rs = 1.0f / s;

  // gather: 2 groups of 128 threads split the support list
  const float* Rb = R + (size_t)b * L_ * D_;
  const int g = t >> 7, c = t & 127;
  float a0 = 0.f;
  int k = g;
  for (; k + 6 < ns; k += 8) {
    int i0 = sJ[k], i1 = sJ[k + 2], i2 = sJ[k + 4], i3 = sJ[k + 6];
    float w0 = sW[k], w1 = sW[k + 2], w2 = sW[k + 4], w3v = sW[k + 6];
    a0 += w0 * Rb[(size_t)i0 * D_ + c] + w1 * Rb[(size_t)i1 * D_ + c]
        + w2 * Rb[(size_t)i2 * D_ + c] + w3v * Rb[(size_t)i3 * D_ + c];
  }
  for (; k < ns; k += 2) a0 += sW[k] * Rb[(size_t)sJ[k] * D_ + c];
  __syncthreads();
  ppart[t] = a0;
  __syncthreads();
  float r = 0.f;
  if (t < 128) {
    float a2 = (ppart[t] + ppart[t + 128]) * rs;
    const float sc = 1.0507009873554805f, al = 1.6732632423543772f;
    r = a2 > 0.f ? sc * a2 : sc * al * (expf(a2) - 1.0f);
  }
  float qq = r * r;
  #pragma unroll
  for (int m = 32; m >= 1; m >>= 1) qq += __shfl_xor(qq, m, 64);
  if (lane == 0) sred[0][wave] = qq;
  __syncthreads();
  if (t < 128) {
    float nrm = sqrtf(sred[0][0] + sred[0][1]);
    out[b * D_ + t] = r / nrm;
  }
}

extern "C" void kernel_launch(void* const* d_in, const int* in_sizes, int n_in,
                              void* d_out, int out_size, void* d_ws, size_t ws_size,
                              hipStream_t stream) {
  const float* R      = (const float*)d_in[0];
  const float* alpha  = (const float*)d_in[1];
  const float* target = (const float*)d_in[2];
  const float* Wr1    = (const float*)d_in[3];
  const float* Wr2    = (const float*)d_in[4];
  const float* Wr3    = (const float*)d_in[5];
  const float* bias_r = (const float*)d_in[6];
  const float* Wf_w   = (const float*)d_in[7];
  const float* Wf_b   = (const float*)d_in[8];
  float* out = (float*)d_out;

  char* ws = (char*)d_ws;
  float* cvec          = (float*)ws;                         // 64 KB
  unsigned short* whi  = (unsigned short*)(ws + 65536);      // 32 KB
  unsigned short* wlo  = (unsigned short*)(ws + 98304);      // 32 KB
  float* scores        = (float*)(ws + 131072);              // 2 MB

  hipLaunchKernelGGL(prep, dim3(128), dim3(256), 0, stream,
                     Wr1, whi, wlo, target, Wr2, bias_r, Wf_w, Wf_b, cvec);
  hipLaunchKernelGGL(pass_b, dim3(B_ * 32), dim3(256), 0, stream,
                     R, whi, wlo, cvec, Wr3, scores);
  hipLaunchKernelGGL(pass_cd, dim3(B_), dim3(256), 0, stream,
                     scores, alpha, R, out);
}

// Round 6
// 493.162 us; speedup vs baseline: 1.7317x; 1.0353x over previous
//
#include <hip/hip_runtime.h>
#include <hip/hip_bf16.h>

#define B_ 128
#define L_ 4096
#define D_ 128
#define E_ 64

typedef __attribute__((ext_vector_type(8))) short short8;
typedef __attribute__((ext_vector_type(4))) float floatx4;

// truncation split: hi = top-16-bit truncation (valid bf16), lo = x - hi (exact),
// lo also truncated to bf16. Combined rel error ~2^-16.
static __device__ __forceinline__ void split_trunc(float x, unsigned short& hs,
                                                   unsigned short& ls) {
  unsigned int bx = __float_as_uint(x);
  float hf = __uint_as_float(bx & 0xffff0000u);
  hs = (unsigned short)(bx >> 16);
  float lo = x - hf;
  ls = (unsigned short)(__float_as_uint(lo) >> 16);
}

// ---------------- kernel 1: scores[b][l] = sum_e Wr3[e]*relu(R[b][l]·Wr1[e] + c[b][e])
// R2-proven structure: scattered-but-line-covering A loads -> trunc split ->
// lane-owned LDS fragment slots (conflict-free b128) -> barrier ->
// 96 MFMA/wave with register-preloaded B; Wr1 fragments converted inline
// from fp32 (L2-hot) and cvec recomputed per block (kills the prep kernel).
__global__ __launch_bounds__(256, 2) void pass_b(
    const float* __restrict__ R, const float* __restrict__ alpha,
    const float* __restrict__ target, const float* __restrict__ Wr1,
    const float* __restrict__ Wr2, const float* __restrict__ Wr3,
    const float* __restrict__ bias_r, const float* __restrict__ Wf_w,
    const float* __restrict__ Wf_b, float* __restrict__ scores) {
  __shared__ __align__(16) unsigned short sAhi[16384];  // 32 KB
  __shared__ __align__(16) unsigned short sAlo[16384];  // 32 KB
  __shared__ float tg[D_];
  __shared__ float qv[E_];
  __shared__ float scvec[D_];

  const int b = blockIdx.x >> 5;
  const int lt = blockIdx.x & 31;
  const int t = threadIdx.x;
  const int wave = t >> 6, lane = t & 63;
  const int col = lane & 15, quad = lane >> 4;

  if (t < D_) tg[t] = target[b * D_ + t];

  // ---- stage A-tile fragments (R tile) hi/lo into lane-owned 16B slots
  const float* Rbase = R + ((size_t)b * L_ + (size_t)lt * 128) * D_;
  #pragma unroll
  for (int i = 0; i < 8; ++i) {
    const int mt = wave * 2 + (i >> 2);
    const int ks = i & 3;
    const int row = mt * 16 + col;
    const int c0 = ks * 32 + quad * 8;
    const float4* p = (const float4*)(Rbase + (size_t)row * D_ + c0);
    float4 v0 = p[0], v1 = p[1];
    float vv[8] = {v0.x, v0.y, v0.z, v0.w, v1.x, v1.y, v1.z, v1.w};
    union { unsigned short u[8]; short8 v; } H, Lo;
    #pragma unroll
    for (int j = 0; j < 8; ++j) split_trunc(vv[j], H.u[j], Lo.u[j]);
    const int base = ((mt * 4 + ks) * 64 + lane) * 8;
    *(short8*)(sAhi + base) = H.v;
    *(short8*)(sAlo + base) = Lo.v;
  }

  // ---- B fragments inline from fp32 Wr1 (L2-hot), trunc split in registers
  short8 bh[2][4], bl[2][4];
  #pragma unroll
  for (int n = 0; n < 2; ++n)
    #pragma unroll
    for (int ks = 0; ks < 4; ++ks) {
      const int e = (wave * 2 + n) * 16 + col;
      const int c0 = ks * 32 + quad * 8;
      const float4* p = (const float4*)(Wr1 + e * D_ + c0);
      float4 v0 = p[0], v1 = p[1];
      float vv[8] = {v0.x, v0.y, v0.z, v0.w, v1.x, v1.y, v1.z, v1.w};
      union { unsigned short u[8]; short8 v; } H, Lo;
      #pragma unroll
      for (int j = 0; j < 8; ++j) split_trunc(vv[j], H.u[j], Lo.u[j]);
      bh[n][ks] = H.v;
      bl[n][ks] = Lo.v;
    }

  floatx4 acc[8][2];
  #pragma unroll
  for (int mt = 0; mt < 8; ++mt)
    #pragma unroll
    for (int n = 0; n < 2; ++n) acc[mt][n] = (floatx4){0.f, 0.f, 0.f, 0.f};

  __syncthreads();  // publishes tg + A tile

  // ---- cvec for this batch (redundant per block, L2-hot weights)
  if (t < E_) {
    float s = Wf_b[t];
    #pragma unroll 8
    for (int d = 0; d < D_; ++d) s += tg[d] * Wf_w[t * D_ + d];
    qv[t] = s;
  }
  __syncthreads();
  if (t < D_) {
    float s = bias_r[t];
    #pragma unroll 8
    for (int e = 0; e < E_; ++e) s += qv[e] * Wr2[t * E_ + e];
    scvec[t] = s;
  }

  // ---- MFMA main loop (split-bf16: hi*hi + lo*hi + hi*lo)
  #pragma unroll
  for (int mt = 0; mt < 8; ++mt) {
    #pragma unroll
    for (int ks = 0; ks < 4; ++ks) {
      const int ai = ((mt * 4 + ks) * 64 + lane) * 8;
      short8 ah = *(const short8*)(sAhi + ai);
      short8 al = *(const short8*)(sAlo + ai);
      #pragma unroll
      for (int n = 0; n < 2; ++n) {
        acc[mt][n] = __builtin_amdgcn_mfma_f32_16x16x32_bf16(ah, bh[n][ks], acc[mt][n], 0, 0, 0);
        acc[mt][n] = __builtin_amdgcn_mfma_f32_16x16x32_bf16(al, bh[n][ks], acc[mt][n], 0, 0, 0);
        acc[mt][n] = __builtin_amdgcn_mfma_f32_16x16x32_bf16(ah, bl[n][ks], acc[mt][n], 0, 0, 0);
      }
    }
  }

  __syncthreads();  // A tile dead; scvec published

  // ---- epilogue: score[m] = sum_e Wr3[e]*relu(C[m][e] + cvec[e])
  float w3[2], cb[2];
  #pragma unroll
  for (int n = 0; n < 2; ++n) {
    const int e = (wave * 2 + n) * 16 + col;
    w3[n] = Wr3[e];
    cb[n] = scvec[e];
  }
  float part[8][4];
  #pragma unroll
  for (int mt = 0; mt < 8; ++mt)
    #pragma unroll
    for (int r = 0; r < 4; ++r) {
      float s = 0.f;
      #pragma unroll
      for (int n = 0; n < 2; ++n)
        s += w3[n] * fmaxf(acc[mt][n][r] + cb[n], 0.f);
      s += __shfl_xor(s, 1, 64);
      s += __shfl_xor(s, 2, 64);
      s += __shfl_xor(s, 4, 64);
      s += __shfl_xor(s, 8, 64);
      part[mt][r] = s;
    }
  float* red = (float*)sAhi;  // [4 waves][128 rows]
  if (col == 0) {
    #pragma unroll
    for (int mt = 0; mt < 8; ++mt)
      #pragma unroll
      for (int r = 0; r < 4; ++r)
        red[wave * 128 + mt * 16 + quad * 4 + r] = part[mt][r];
  }
  __syncthreads();
  if (t < 128) {
    float s = (red[t] + red[128 + t]) + (red[256 + t] + red[384 + t]);
    scores[(size_t)b * L_ + lt * 128 + t] = s;
  }
}

// ---------------- kernel 2: entmax bisection (24 iters) + support gather +
// selu + L2-normalize. 512 threads, 8 elems/thread.
__global__ __launch_bounds__(512) void pass_cd(
    const float* __restrict__ scores, const float* __restrict__ alpha,
    const float* __restrict__ R, float* __restrict__ out) {
  const int b = blockIdx.x, t = threadIdx.x;
  const int wave = t >> 6, lane = t & 63;
  __shared__ float sred[2][8];
  __shared__ unsigned short sidx[L_];
  __shared__ float sw[L_];
  __shared__ float ppart[512];
  __shared__ int scnt;
  const float am1 = alpha[b] - 1.0f;
  const float inv = 1.0f / am1;
  const float* S = scores + (size_t)b * L_;
  float Xs[8];
  #pragma unroll
  for (int i = 0; i < 8; ++i) Xs[i] = S[i * 512 + t] * am1;
  if (t == 0) scnt = 0;

  // block max
  float mx = Xs[0];
  #pragma unroll
  for (int i = 1; i < 8; ++i) mx = fmaxf(mx, Xs[i]);
  #pragma unroll
  for (int m = 32; m >= 1; m >>= 1) mx = fmaxf(mx, __shfl_xor(mx, m, 64));
  if (lane == 0) sred[0][wave] = mx;
  __syncthreads();
  mx = sred[0][0];
  #pragma unroll
  for (int w = 1; w < 8; ++w) mx = fmaxf(mx, sred[0][w]);

  float tau_lo = mx - 1.0f;
  float dm = (mx - exp2f(-12.0f * am1)) - tau_lo;  // tau_hi - tau_lo

  int pc = 1;  // parity counter (buffer 0 used by max)
  auto sumP = [&](float tau) -> float {
    const int par = pc & 1;
    ++pc;
    float s = 0.f;
    #pragma unroll
    for (int i = 0; i < 8; ++i) {
      float u = Xs[i] - tau;
      if (u > 0.f) s += exp2f(inv * __log2f(u));
    }
    #pragma unroll
    for (int m = 32; m >= 1; m >>= 1) s += __shfl_xor(s, m, 64);
    if (lane == 0) sred[par][wave] = s;
    __syncthreads();
    float r = sred[par][0];
    #pragma unroll
    for (int w = 1; w < 8; ++w) r += sred[par][w];
    return r;
  };

  const float f_lo = sumP(tau_lo) - 1.0f;
  float tau_m = tau_lo;
  for (int it = 0; it < 24; ++it) {  // dtau = bracket*2^-24: output shift << thresh
    dm *= 0.5f;
    tau_m = tau_lo + dm;
    float f_m = sumP(tau_m) - 1.0f;
    if (f_m * f_lo >= 0.f) tau_lo = tau_m;  // uniform branch
  }

  // final p, compact support, normalization sum
  float s = 0.f;
  #pragma unroll
  for (int i = 0; i < 8; ++i) {
    float u = Xs[i] - tau_m;
    if (u > 0.f) {
      float p = exp2f(inv * __log2f(u));
      s += p;
      int pos = atomicAdd(&scnt, 1);
      sidx[pos] = (unsigned short)(i * 512 + t);
      sw[pos] = p;
    }
  }
  {
    const int par = pc & 1;
    ++pc;
    #pragma unroll
    for (int m = 32; m >= 1; m >>= 1) s += __shfl_xor(s, m, 64);
    if (lane == 0) sred[par][wave] = s;
    __syncthreads();  // publishes sidx/sw/scnt too
    s = sred[par][0];
    #pragma unroll
    for (int w = 1; w < 8; ++w) s += sred[par][w];
  }
  const int ns = scnt;
  const float rs = 1.0f / s;

  // gather: 4 groups of 128 threads split the support list
  const float* Rb = R + (size_t)b * L_ * D_;
  const int g = t >> 7, c = t & 127;
  float acc = 0.f;
  int k = g;
  for (; k + 4 < ns; k += 8) {
    int i0 = sidx[k], i1 = sidx[k + 4];
    float w0 = sw[k], w1 = sw[k + 4];
    acc += w0 * Rb[(size_t)i0 * D_ + c] + w1 * Rb[(size_t)i1 * D_ + c];
  }
  for (; k < ns; k += 4) acc += sw[k] * Rb[(size_t)sidx[k] * D_ + c];
  __syncthreads();
  ppart[t] = acc;
  __syncthreads();
  float r = 0.f;
  if (t < 128) {
    float a2 = ((ppart[t] + ppart[t + 128]) + (ppart[t + 256] + ppart[t + 384])) * rs;
    const float sc = 1.0507009873554805f, al = 1.6732632423543772f;
    r = a2 > 0.f ? sc * a2 : sc * al * (expf(a2) - 1.0f);
  }
  float q = r * r;
  #pragma unroll
  for (int m = 32; m >= 1; m >>= 1) q += __shfl_xor(q, m, 64);
  if (lane == 0) sred[0][wave] = q;
  __syncthreads();
  if (t < 128) {
    float nrm = sqrtf(sred[0][0] + sred[0][1]);
    out[b * D_ + t] = r / nrm;
  }
}

extern "C" void kernel_launch(void* const* d_in, const int* in_sizes, int n_in,
                              void* d_out, int out_size, void* d_ws, size_t ws_size,
                              hipStream_t stream) {
  const float* R      = (const float*)d_in[0];
  const float* alpha  = (const float*)d_in[1];
  const float* target = (const float*)d_in[2];
  const float* Wr1    = (const float*)d_in[3];
  const float* Wr2    = (const float*)d_in[4];
  const float* Wr3    = (const float*)d_in[5];
  const float* bias_r = (const float*)d_in[6];
  const float* Wf_w   = (const float*)d_in[7];
  const float* Wf_b   = (const float*)d_in[8];
  float* out = (float*)d_out;

  float* scores = (float*)d_ws;  // 2 MB

  hipLaunchKernelGGL(pass_b, dim3(B_ * 32), dim3(256), 0, stream,
                     R, alpha, target, Wr1, Wr2, Wr3, bias_r, Wf_w, Wf_b, scores);
  hipLaunchKernelGGL(pass_cd, dim3(B_), dim3(512), 0, stream,
                     scores, alpha, R, out);
}

// Round 7
// 427.895 us; speedup vs baseline: 1.9959x; 1.1525x over previous
//
#include <hip/hip_runtime.h>
#include <hip/hip_bf16.h>

#define B_ 128
#define L_ 4096
#define D_ 128
#define E_ 64

typedef __attribute__((ext_vector_type(8))) short short8;
typedef __attribute__((ext_vector_type(4))) float floatx4;

// truncation split: hi = top-16-bit truncation (valid bf16), lo = x - hi (exact),
// lo also truncated to bf16. Combined rel error ~2^-16.
static __device__ __forceinline__ void split_trunc(float x, unsigned short& hs,
                                                   unsigned short& ls) {
  unsigned int bx = __float_as_uint(x);
  float hf = __uint_as_float(bx & 0xffff0000u);
  hs = (unsigned short)(bx >> 16);
  float lo = x - hf;
  ls = (unsigned short)(__float_as_uint(lo) >> 16);
}

// ---------------- prep: blocks 0..63 split+swizzle Wr1; blocks 64..127 compute
// cvec[b][d] = bias_r[d] + sum_e (target[b]·Wf_w[e] + Wf_b[e]) * Wr2[d][e]
__global__ __launch_bounds__(256) void prep(
    const float* __restrict__ Wr1, unsigned short* __restrict__ hi,
    unsigned short* __restrict__ lo, const float* __restrict__ target,
    const float* __restrict__ Wr2, const float* __restrict__ bias_r,
    const float* __restrict__ Wf_w, const float* __restrict__ Wf_b,
    float* __restrict__ cvec) {
  if (blockIdx.x < 64) {
    // B operand fragments: B[k=d][n=e] = Wr1[e][d]; dst [nt(8)][ks(4)][lane(64)][j(8)]
    int t = blockIdx.x * 256 + threadIdx.x;  // 0..16383
    int j = t & 7, lane = (t >> 3) & 63, ks = (t >> 9) & 3, nt = t >> 11;
    int e = nt * 16 + (lane & 15);
    int d = ks * 32 + (lane >> 4) * 8 + j;
    split_trunc(Wr1[e * D_ + d], hi[t], lo[t]);
  } else {
    const int sub = threadIdx.x >> 7;           // 2 batches per block
    const int t = threadIdx.x & 127;
    const int b = (blockIdx.x - 64) * 2 + sub;
    __shared__ float tg[2][D_];
    __shared__ float q[2][E_];
    tg[sub][t] = target[b * D_ + t];
    __syncthreads();
    if (t < E_) {
      float s = Wf_b[t];
      #pragma unroll 8
      for (int d = 0; d < D_; ++d) s += tg[sub][d] * Wf_w[t * D_ + d];
      q[sub][t] = s;
    }
    __syncthreads();
    float s = bias_r[t];
    #pragma unroll 8
    for (int e = 0; e < E_; ++e) s += q[sub][e] * Wr2[t * E_ + e];
    cvec[b * D_ + t] = s;
  }
}

// ---------------- pass B: scores[b][l] = sum_e Wr3[e]*relu( R[b][l]·Wr1[e] + c[b][e] )
// BM=64 tile, 8192 blocks, 4 blocks/CU (LDS 33 KB). Wave w stages m-tile w
// (lane-owned conflict-free b128 slots); every wave computes all 4 m-tiles
// for its 2 n-tiles with register-preloaded pre-split B.
__global__ __launch_bounds__(256, 4) void pass_b(
    const float* __restrict__ R, const unsigned short* __restrict__ Whi,
    const unsigned short* __restrict__ Wlo, const float* __restrict__ cvec,
    const float* __restrict__ Wr3, float* __restrict__ scores) {
  __shared__ __align__(16) unsigned short sAhi[8192];  // 16 KB (64x128 hi)
  __shared__ __align__(16) unsigned short sAlo[8192];  // 16 KB (64x128 lo)
  __shared__ float red[256];                           // cross-wave reduce

  const int b = blockIdx.x >> 6;
  const int lt = blockIdx.x & 63;
  const int t = threadIdx.x;
  const int wave = t >> 6, lane = t & 63;
  const int col = lane & 15, quad = lane >> 4;

  // early L2-hot scalars (latency overlaps staging)
  float w3[2], cb[2];
  #pragma unroll
  for (int n = 0; n < 2; ++n) {
    const int e = (wave * 2 + n) * 16 + col;
    w3[n] = Wr3[e];
    cb[n] = cvec[b * D_ + e];
  }

  // ---- stage A tile: wave w owns m-tile w (rows lt*64 + w*16 + col)
  const float* Rbase = R + ((size_t)b * L_ + (size_t)lt * 64) * D_;
  #pragma unroll
  for (int ks = 0; ks < 4; ++ks) {
    const int row = wave * 16 + col;
    const int c0 = ks * 32 + quad * 8;
    const float4* p = (const float4*)(Rbase + (size_t)row * D_ + c0);
    float4 v0 = p[0], v1 = p[1];
    float vv[8] = {v0.x, v0.y, v0.z, v0.w, v1.x, v1.y, v1.z, v1.w};
    union { unsigned short u[8]; short8 v; } H, Lo;
    #pragma unroll
    for (int j = 0; j < 8; ++j) split_trunc(vv[j], H.u[j], Lo.u[j]);
    const int base = ((wave * 4 + ks) * 64 + lane) * 8;
    *(short8*)(sAhi + base) = H.v;
    *(short8*)(sAlo + base) = Lo.v;
  }

  // ---- preload this wave's pre-split B fragments (2 nt x 4 ks, hi+lo)
  short8 bh[2][4], bl[2][4];
  #pragma unroll
  for (int n = 0; n < 2; ++n)
    #pragma unroll
    for (int ks = 0; ks < 4; ++ks) {
      const int off = (((wave * 2 + n) * 4 + ks) * 64 + lane) * 8;
      bh[n][ks] = *(const short8*)(Whi + off);
      bl[n][ks] = *(const short8*)(Wlo + off);
    }

  floatx4 acc[4][2];
  #pragma unroll
  for (int mt = 0; mt < 4; ++mt)
    #pragma unroll
    for (int n = 0; n < 2; ++n) acc[mt][n] = (floatx4){0.f, 0.f, 0.f, 0.f};

  __syncthreads();

  // ---- MFMA loop (split-bf16: hi*hi + lo*hi + hi*lo)
  #pragma unroll
  for (int mt = 0; mt < 4; ++mt) {
    #pragma unroll
    for (int ks = 0; ks < 4; ++ks) {
      const int ai = ((mt * 4 + ks) * 64 + lane) * 8;
      short8 ah = *(const short8*)(sAhi + ai);
      short8 al = *(const short8*)(sAlo + ai);
      #pragma unroll
      for (int n = 0; n < 2; ++n) {
        acc[mt][n] = __builtin_amdgcn_mfma_f32_16x16x32_bf16(ah, bh[n][ks], acc[mt][n], 0, 0, 0);
        acc[mt][n] = __builtin_amdgcn_mfma_f32_16x16x32_bf16(al, bh[n][ks], acc[mt][n], 0, 0, 0);
        acc[mt][n] = __builtin_amdgcn_mfma_f32_16x16x32_bf16(ah, bl[n][ks], acc[mt][n], 0, 0, 0);
      }
    }
  }

  // ---- epilogue: score[m] = sum_e Wr3[e]*relu(C[m][e] + cvec[e])
  float part[4][4];
  #pragma unroll
  for (int mt = 0; mt < 4; ++mt)
    #pragma unroll
    for (int r = 0; r < 4; ++r) {
      float s = 0.f;
      #pragma unroll
      for (int n = 0; n < 2; ++n)
        s += w3[n] * fmaxf(acc[mt][n][r] + cb[n], 0.f);
      s += __shfl_xor(s, 1, 64);
      s += __shfl_xor(s, 2, 64);
      s += __shfl_xor(s, 4, 64);
      s += __shfl_xor(s, 8, 64);
      part[mt][r] = s;
    }
  __syncthreads();   // LDS A-tile dead before red reuse? red is separate; this
                     // barrier orders red writes after all waves' LDS reads.
  if (col == 0) {
    #pragma unroll
    for (int mt = 0; mt < 4; ++mt)
      #pragma unroll
      for (int r = 0; r < 4; ++r)
        red[wave * 64 + mt * 16 + quad * 4 + r] = part[mt][r];
  }
  __syncthreads();
  if (t < 64) {
    float s = (red[t] + red[64 + t]) + (red[128 + t] + red[192 + t]);
    scores[(size_t)b * L_ + lt * 64 + t] = s;
  }
}

// ---------------- kernel 2: entmax bisection (24 iters) + support gather +
// selu + L2-normalize. 512 threads, 8 elems/thread.
__global__ __launch_bounds__(512) void pass_cd(
    const float* __restrict__ scores, const float* __restrict__ alpha,
    const float* __restrict__ R, float* __restrict__ out) {
  const int b = blockIdx.x, t = threadIdx.x;
  const int wave = t >> 6, lane = t & 63;
  __shared__ float sred[2][8];
  __shared__ unsigned short sidx[L_];
  __shared__ float sw[L_];
  __shared__ float ppart[512];
  __shared__ int scnt;
  const float am1 = alpha[b] - 1.0f;
  const float inv = 1.0f / am1;
  const float* S = scores + (size_t)b * L_;
  float Xs[8];
  #pragma unroll
  for (int i = 0; i < 8; ++i) Xs[i] = S[i * 512 + t] * am1;
  if (t == 0) scnt = 0;

  // block max
  float mx = Xs[0];
  #pragma unroll
  for (int i = 1; i < 8; ++i) mx = fmaxf(mx, Xs[i]);
  #pragma unroll
  for (int m = 32; m >= 1; m >>= 1) mx = fmaxf(mx, __shfl_xor(mx, m, 64));
  if (lane == 0) sred[0][wave] = mx;
  __syncthreads();
  mx = sred[0][0];
  #pragma unroll
  for (int w = 1; w < 8; ++w) mx = fmaxf(mx, sred[0][w]);

  float tau_lo = mx - 1.0f;
  float dm = (mx - exp2f(-12.0f * am1)) - tau_lo;  // tau_hi - tau_lo

  int pc = 1;  // parity counter (buffer 0 used by max)
  auto sumP = [&](float tau) -> float {
    const int par = pc & 1;
    ++pc;
    float s = 0.f;
    #pragma unroll
    for (int i = 0; i < 8; ++i) {
      float u = Xs[i] - tau;
      if (u > 0.f) s += exp2f(inv * __log2f(u));
    }
    #pragma unroll
    for (int m = 32; m >= 1; m >>= 1) s += __shfl_xor(s, m, 64);
    if (lane == 0) sred[par][wave] = s;
    __syncthreads();
    float r = sred[par][0];
    #pragma unroll
    for (int w = 1; w < 8; ++w) r += sred[par][w];
    return r;
  };

  const float f_lo = sumP(tau_lo) - 1.0f;
  float tau_m = tau_lo;
  for (int it = 0; it < 24; ++it) {  // dtau = bracket*2^-24: output shift << thresh
    dm *= 0.5f;
    tau_m = tau_lo + dm;
    float f_m = sumP(tau_m) - 1.0f;
    if (f_m * f_lo >= 0.f) tau_lo = tau_m;  // uniform branch
  }

  // final p, compact support, normalization sum
  float s = 0.f;
  #pragma unroll
  for (int i = 0; i < 8; ++i) {
    float u = Xs[i] - tau_m;
    if (u > 0.f) {
      float p = exp2f(inv * __log2f(u));
      s += p;
      int pos = atomicAdd(&scnt, 1);
      sidx[pos] = (unsigned short)(i * 512 + t);
      sw[pos] = p;
    }
  }
  {
    const int par = pc & 1;
    ++pc;
    #pragma unroll
    for (int m = 32; m >= 1; m >>= 1) s += __shfl_xor(s, m, 64);
    if (lane == 0) sred[par][wave] = s;
    __syncthreads();  // publishes sidx/sw/scnt too
    s = sred[par][0];
    #pragma unroll
    for (int w = 1; w < 8; ++w) s += sred[par][w];
  }
  const int ns = scnt;
  const float rs = 1.0f / s;

  // gather: 4 groups of 128 threads split the support list
  const float* Rb = R + (size_t)b * L_ * D_;
  const int g = t >> 7, c = t & 127;
  float acc = 0.f;
  int k = g;
  for (; k + 4 < ns; k += 8) {
    int i0 = sidx[k], i1 = sidx[k + 4];
    float w0 = sw[k], w1 = sw[k + 4];
    acc += w0 * Rb[(size_t)i0 * D_ + c] + w1 * Rb[(size_t)i1 * D_ + c];
  }
  for (; k < ns; k += 4) acc += sw[k] * Rb[(size_t)sidx[k] * D_ + c];
  __syncthreads();
  ppart[t] = acc;
  __syncthreads();
  float r = 0.f;
  if (t < 128) {
    float a2 = ((ppart[t] + ppart[t + 128]) + (ppart[t + 256] + ppart[t + 384])) * rs;
    const float sc = 1.0507009873554805f, al = 1.6732632423543772f;
    r = a2 > 0.f ? sc * a2 : sc * al * (expf(a2) - 1.0f);
  }
  float q = r * r;
  #pragma unroll
  for (int m = 32; m >= 1; m >>= 1) q += __shfl_xor(q, m, 64);
  if (lane == 0) sred[0][wave] = q;
  __syncthreads();
  if (t < 128) {
    float nrm = sqrtf(sred[0][0] + sred[0][1]);
    out[b * D_ + t] = r / nrm;
  }
}

extern "C" void kernel_launch(void* const* d_in, const int* in_sizes, int n_in,
                              void* d_out, int out_size, void* d_ws, size_t ws_size,
                              hipStream_t stream) {
  const float* R      = (const float*)d_in[0];
  const float* alpha  = (const float*)d_in[1];
  const float* target = (const float*)d_in[2];
  const float* Wr1    = (const float*)d_in[3];
  const float* Wr2    = (const float*)d_in[4];
  const float* Wr3    = (const float*)d_in[5];
  const float* bias_r = (const float*)d_in[6];
  const float* Wf_w   = (const float*)d_in[7];
  const float* Wf_b   = (const float*)d_in[8];
  float* out = (float*)d_out;

  char* ws = (char*)d_ws;
  float* cvec          = (float*)ws;                         // 64 KB
  unsigned short* whi  = (unsigned short*)(ws + 65536);      // 32 KB
  unsigned short* wlo  = (unsigned short*)(ws + 98304);      // 32 KB
  float* scores        = (float*)(ws + 131072);              // 2 MB

  hipLaunchKernelGGL(prep, dim3(128), dim3(256), 0, stream,
                     Wr1, whi, wlo, target, Wr2, bias_r, Wf_w, Wf_b, cvec);
  hipLaunchKernelGGL(pass_b, dim3(B_ * 64), dim3(256), 0, stream,
                     R, whi, wlo, cvec, Wr3, scores);
  hipLaunchKernelGGL(pass_cd, dim3(B_), dim3(512), 0, stream,
                     scores, alpha, R, out);
}